// Round 9
// baseline (276.325 us; speedup 1.0000x reference)
//
#include <hip/hip_runtime.h>
#include <cmath>

#define Bdim 8
#define Cdim 768
#define Kdim 256
#define Ndim 4096
#define NT 64      // tokens per block in kernel 1
#define KC2 32     // C-chunk per MFMA stage (3-buffered)
#define NCH (Cdim / KC2)   // 24
#define CB2 4      // c-rows per block in kernel 2
#define NCOPY 4    // replicated LDS accumulators in kernel 2

typedef __bf16 bf16x8 __attribute__((ext_vector_type(8)));
typedef short  s16x8  __attribute__((ext_vector_type(8)));
typedef float  f32x4  __attribute__((ext_vector_type(4)));
union U8 { s16x8 s; bf16x8 b; };

// direct global->LDS DMA, 16B per lane, wave-uniform LDS base
typedef __attribute__((address_space(1))) const unsigned int g_u32;
typedef __attribute__((address_space(3))) unsigned int l_u32;
__device__ __forceinline__ void gload16(const void* g, void* l) {
    __builtin_amdgcn_global_load_lds((g_u32*)g, (l_u32*)l, 16, 0, 0);
}

// three-level bf16 split, RNE at each level; v = h + m + l + eps, |eps| <= 2^-27 |v|
__device__ __forceinline__ void split3(float v, short& h, short& m, short& l) {
    unsigned u = __float_as_uint(v);
    unsigned th = u + 0x7FFFu + ((u >> 16) & 1u);
    h = (short)(th >> 16);
    float r1 = v - __uint_as_float(th & 0xFFFF0000u);      // exact
    unsigned u1 = __float_as_uint(r1);
    unsigned tm = u1 + 0x7FFFu + ((u1 >> 16) & 1u);
    m = (short)(tm >> 16);
    float r2 = r1 - __uint_as_float(tm & 0xFFFF0000u);     // exact
    unsigned u2 = __float_as_uint(r2);
    unsigned tl = u2 + 0x7FFFu + ((u2 >> 16) & 1u);
    l = (short)(tl >> 16);
}

// Prep: per batch b — centroid inverse norms (fp32, exact) + zero cnt.
__global__ __launch_bounds__(256) void prep_kernel(
    const float* __restrict__ cents, float* __restrict__ invc, int* __restrict__ cnt)
{
    __shared__ float red[4][Kdim];
    const int tid = threadIdx.x;
    const int b = blockIdx.x;
    const float* cb = cents + (size_t)b * Cdim * Kdim;
    const int q = tid & 63, g = tid >> 6;
    float4 ss = make_float4(0.f, 0.f, 0.f, 0.f);
    for (int r = g; r < Cdim; r += 4) {
        float4 v = *(const float4*)(cb + (size_t)r * Kdim + q * 4);
        ss.x = fmaf(v.x, v.x, ss.x); ss.y = fmaf(v.y, v.y, ss.y);
        ss.z = fmaf(v.z, v.z, ss.z); ss.w = fmaf(v.w, v.w, ss.w);
    }
    *(float4*)&red[g][q * 4] = ss;
    __syncthreads();
    float s = red[0][tid] + red[1][tid] + red[2][tid] + red[3][tid];
    invc[b * Kdim + tid] = 1.f / fmaxf(sqrtf(s), 1e-12f);
    cnt[b * Kdim + tid] = 0;
}

// Cvt: centroids -> split-3 bf16 planes in MFMA-fragment layout
// plane[(b*96 + c/8)*256 + k][8]: 8 consecutive c per 16B record.
__global__ __launch_bounds__(256) void cvt_kernel(
    const float* __restrict__ cents, short* __restrict__ centH,
    short* __restrict__ centM, short* __restrict__ centL)
{
    const int k = threadIdx.x;
    const int bc = blockIdx.x;                    // b*96 + c8
    const float* src = cents + ((size_t)(bc / 96) * Cdim + (size_t)(bc % 96) * 8) * Kdim + k;
    s16x8 H, M, L;
    #pragma unroll
    for (int e = 0; e < 8; ++e) {
        short h, m, l;
        split3(src[(size_t)e * Kdim], h, m, l);   // coalesced across lanes (k)
        H[e] = h; M[e] = m; L[e] = l;
    }
    ((s16x8*)centH)[(size_t)bc * 256 + k] = H;    // 16B coalesced stores
    ((s16x8*)centM)[(size_t)bc * 256 + k] = M;
    ((s16x8*)centL)[(size_t)bc * 256 + k] = L;
}

// Kernel 1: per (b, n-tile of 64): cos via split-3 bf16 MFMA, 6 passes
// (hh, hm, mh, hl, lh, mm) into ONE accumulator (noise ~1.5e-8 cos, safe).
// __launch_bounds__(256,2): 2 waves/SIMD is the grid cap anyway; this frees
// the full ~256-VGPR budget so acc + 24 fragments stay live (no remat).
__global__ __launch_bounds__(256, 2) void sim_mfma_kernel(
    const float* __restrict__ x,        // (B,C,N) fp32
    const short* __restrict__ centH,
    const short* __restrict__ centM,
    const short* __restrict__ centL,
    const float* __restrict__ alpha_p,
    const float* __restrict__ beta_p,
    const float* __restrict__ invc,     // (B,K) fp32
    float* __restrict__ simOut,         // (B,K,N), pre-zeroed
    float* __restrict__ wArr,
    int*   __restrict__ kArr,
    int*   __restrict__ cnt)
{
    __shared__ __align__(16) float sxf[3][KC2][NT];  // 24 KB fp32 x chunks
    __shared__ float invcS[Kdim];
    __shared__ float px[4][NT];
    __shared__ float invxS[NT];
    __shared__ float bwv[4][NT];
    __shared__ int   bwk[4][NT];

    const int tid  = threadIdx.x;
    const int lane = tid & 63;
    const int w    = tid >> 6;          // wave id: k-range [w*64, w*64+64)
    const int q    = lane >> 4;         // 0..3
    const int c15  = lane & 15;
    const int b    = blockIdx.x >> 6;
    const int n0   = (blockIdx.x & 63) * NT;
    const float* xb = x + (size_t)b * Cdim * Ndim;

    invcS[tid] = invc[b * Kdim + tid];
    const float alpha = alpha_p[0];
    const float beta  = beta_p[0];

    f32x4 acc[4][4];
    #pragma unroll
    for (int i = 0; i < 4; ++i)
        #pragma unroll
        for (int j = 0; j < 4; ++j) acc[i][j] = (f32x4){0.f, 0.f, 0.f, 0.f};

    float xn2p = 0.f;

    // exactly 2 DMA (vmcnt) ops per wave per STAGE
    #define STAGE(t_) do {                                                    \
        const int bf_ = (t_) % 3; const int c0_ = (t_) * KC2;                 \
        _Pragma("unroll")                                                     \
        for (int i_ = 0; i_ < 2; ++i_)                                        \
            gload16(xb + (size_t)(c0_ + w * 8 + i_ * 4 + q) * Ndim            \
                       + n0 + c15 * 4,                                        \
                    &sxf[bf_][w * 8 + i_ * 4][0]);                            \
    } while (0)

    STAGE(0);
    STAGE(1);

    const s16x8* cHb = (const s16x8*)centH + ((size_t)b * 96) * 256;
    const s16x8* cMb = (const s16x8*)centM + ((size_t)b * 96) * 256;
    const s16x8* cLb = (const s16x8*)centL + ((size_t)b * 96) * 256;

    for (int t = 0; t < NCH; ++t) {
        // retire everything except STAGE(t+1)'s 2 newest; chunk t ready
        asm volatile("s_waitcnt vmcnt(2)" ::: "memory");
        __builtin_amdgcn_s_barrier();
        __builtin_amdgcn_sched_barrier(0);

        const int cur = t % 3;

        // A fragments (12 16B loads, L2/L3-resident planes), before next STAGE
        U8 aH[4], aM[4], aL[4];
        {
            const size_t rowb = ((size_t)(t * 4 + q)) * 256 + w * 64 + c15;
            #pragma unroll
            for (int kf = 0; kf < 4; ++kf) {
                aH[kf].s = cHb[rowb + kf * 16];
                aM[kf].s = cMb[rowb + kf * 16];
                aL[kf].s = cLb[rowb + kf * 16];
            }
        }
        if (t + 2 < NCH) STAGE(t + 2);

        // x-norm partials (rows w*8..w*8+7, col = lane)
        #pragma unroll
        for (int r = 0; r < 8; ++r) {
            float v = sxf[cur][w * 8 + r][lane];
            xn2p = fmaf(v, v, xn2p);
        }

        // B fragments: split fp32 tile -> h/m/l bf16 in-register
        U8 bH[4], bM[4], bL[4];
        #pragma unroll
        for (int nf = 0; nf < 4; ++nf) {
            #pragma unroll
            for (int e = 0; e < 8; ++e) {
                short h, m, l;
                split3(sxf[cur][q * 8 + e][nf * 16 + c15], h, m, l);
                bH[nf].s[e] = h; bM[nf].s[e] = m; bL[nf].s[e] = l;
            }
        }

        // 6 passes x 16 fragment-MFMAs, pass-major, single accumulator
        #pragma unroll
        for (int kf = 0; kf < 4; ++kf)
            #pragma unroll
            for (int nf = 0; nf < 4; ++nf)
                acc[kf][nf] = __builtin_amdgcn_mfma_f32_16x16x32_bf16(
                    aH[kf].b, bH[nf].b, acc[kf][nf], 0, 0, 0);
        #pragma unroll
        for (int kf = 0; kf < 4; ++kf)
            #pragma unroll
            for (int nf = 0; nf < 4; ++nf)
                acc[kf][nf] = __builtin_amdgcn_mfma_f32_16x16x32_bf16(
                    aH[kf].b, bM[nf].b, acc[kf][nf], 0, 0, 0);
        #pragma unroll
        for (int kf = 0; kf < 4; ++kf)
            #pragma unroll
            for (int nf = 0; nf < 4; ++nf)
                acc[kf][nf] = __builtin_amdgcn_mfma_f32_16x16x32_bf16(
                    aM[kf].b, bH[nf].b, acc[kf][nf], 0, 0, 0);
        #pragma unroll
        for (int kf = 0; kf < 4; ++kf)
            #pragma unroll
            for (int nf = 0; nf < 4; ++nf)
                acc[kf][nf] = __builtin_amdgcn_mfma_f32_16x16x32_bf16(
                    aH[kf].b, bL[nf].b, acc[kf][nf], 0, 0, 0);
        #pragma unroll
        for (int kf = 0; kf < 4; ++kf)
            #pragma unroll
            for (int nf = 0; nf < 4; ++nf)
                acc[kf][nf] = __builtin_amdgcn_mfma_f32_16x16x32_bf16(
                    aL[kf].b, bH[nf].b, acc[kf][nf], 0, 0, 0);
        #pragma unroll
        for (int kf = 0; kf < 4; ++kf)
            #pragma unroll
            for (int nf = 0; nf < 4; ++nf)
                acc[kf][nf] = __builtin_amdgcn_mfma_f32_16x16x32_bf16(
                    aM[kf].b, bM[nf].b, acc[kf][nf], 0, 0, 0);
    }
    #undef STAGE

    __syncthreads();
    px[w][lane] = xn2p;
    __syncthreads();
    if (tid < NT) {
        float s = px[0][tid] + px[1][tid] + px[2][tid] + px[3][tid];
        invxS[tid] = 1.f / fmaxf(sqrtf(s), 1e-12f);
    }
    __syncthreads();

    // epilogue: cos -> sigmoid -> argmax (first-win = min-k on ties)
    // D layout: row(k_local) = q*4 + reg, col(n) = c15
    #pragma unroll
    for (int nf = 0; nf < 4; ++nf) {
        const float ivx = invxS[nf * 16 + c15];
        float best = -1.f; int bk = 0;
        #pragma unroll
        for (int kf = 0; kf < 4; ++kf) {
            float4 ic = *(const float4*)&invcS[w * 64 + kf * 16 + q * 4];
            #pragma unroll
            for (int r = 0; r < 4; ++r) {
                float cosv = acc[kf][nf][r] * ((const float*)&ic)[r] * ivx;
                float s = 1.f / (1.f + expf(-(beta + alpha * cosv)));
                int k = w * 64 + kf * 16 + q * 4 + r;
                if (s > best) { best = s; bk = k; }   // ascending k scan
            }
        }
        // reduce across q-groups (lanes l, l^16, l^32, l^48 share n)
        #pragma unroll
        for (int off = 16; off < 64; off <<= 1) {
            float ov = __shfl_xor(best, off);
            int   ok = __shfl_xor(bk, off);
            if (ov > best || (ov == best && ok < bk)) { best = ov; bk = ok; }
        }
        if (q == 0) { bwv[w][nf * 16 + c15] = best; bwk[w][nf * 16 + c15] = bk; }
    }
    __syncthreads();
    if (tid < NT) {
        float best = -1.f; int bk = 0;
        #pragma unroll
        for (int g = 0; g < 4; ++g) {    // ascending waves = ascending k
            float v = bwv[g][tid];
            if (v > best) { best = v; bk = bwk[g][tid]; }
        }
        int gn = b * Ndim + n0 + tid;
        wArr[gn] = best;
        kArr[gn] = bk;
        simOut[((size_t)(b * Kdim + bk)) * Ndim + n0 + tid] = best;
        atomicAdd(&cnt[b * Kdim + bk], 1);
    }
}

// Kernel 2: per (b, 4 c-rows): ALL 24 16B loads issued up-front into named
// registers (one latency exposure per block), then LDS-atomic scatter in
// load order. launch_bounds(256,4) -> <=128 VGPR, ~4 blocks/CU.
__global__ __launch_bounds__(256, 4) void agg_kernel(
    const float* __restrict__ x, const float* __restrict__ cents,
    const float* __restrict__ wArr, const int* __restrict__ kArr,
    const int* __restrict__ cnt, float* __restrict__ hyp)
{
    __shared__ float accs[NCOPY][CB2][Kdim + 1];
    const int tid = threadIdx.x;
    const int b  = blockIdx.x / (Cdim / CB2);
    const int c0 = (blockIdx.x % (Cdim / CB2)) * CB2;
    const int cp = tid & 3;
    const float* xb = x + ((size_t)b * Cdim + c0) * Ndim;

    // Phase 1: issue ALL loads (4 token-quads x {k, w, 4 x-rows})
    const int n0_ = (tid + 0 * 256) * 4, n1_ = (tid + 1 * 256) * 4;
    const int n2_ = (tid + 2 * 256) * 4, n3_ = (tid + 3 * 256) * 4;
    int4   kv0 = *(const int4*)&kArr[b * Ndim + n0_];
    int4   kv1 = *(const int4*)&kArr[b * Ndim + n1_];
    int4   kv2 = *(const int4*)&kArr[b * Ndim + n2_];
    int4   kv3 = *(const int4*)&kArr[b * Ndim + n3_];
    float4 w40 = *(const float4*)&wArr[b * Ndim + n0_];
    float4 w41 = *(const float4*)&wArr[b * Ndim + n1_];
    float4 w42 = *(const float4*)&wArr[b * Ndim + n2_];
    float4 w43 = *(const float4*)&wArr[b * Ndim + n3_];
    float4 xv0[CB2], xv1[CB2], xv2[CB2], xv3[CB2];
    #pragma unroll
    for (int r = 0; r < CB2; ++r) xv0[r] = *(const float4*)&xb[(size_t)r * Ndim + n0_];
    #pragma unroll
    for (int r = 0; r < CB2; ++r) xv1[r] = *(const float4*)&xb[(size_t)r * Ndim + n1_];
    #pragma unroll
    for (int r = 0; r < CB2; ++r) xv2[r] = *(const float4*)&xb[(size_t)r * Ndim + n2_];
    #pragma unroll
    for (int r = 0; r < CB2; ++r) xv3[r] = *(const float4*)&xb[(size_t)r * Ndim + n3_];

    // zero-init overlaps the load latency (loads are global, init is LDS)
    for (int i = tid; i < NCOPY * CB2 * (Kdim + 1); i += 256) ((float*)accs)[i] = 0.f;
    __syncthreads();

    // Phase 2: LDS-atomic scatter, in load-retirement order
    #define SCAT(kv, w4, xv)                                                  \
        _Pragma("unroll")                                                     \
        for (int r = 0; r < CB2; ++r) {                                       \
            atomicAdd(&accs[cp][r][kv.x], w4.x * xv[r].x);                    \
            atomicAdd(&accs[cp][r][kv.y], w4.y * xv[r].y);                    \
            atomicAdd(&accs[cp][r][kv.z], w4.z * xv[r].z);                    \
            atomicAdd(&accs[cp][r][kv.w], w4.w * xv[r].w);                    \
        }
    SCAT(kv0, w40, xv0)
    SCAT(kv1, w41, xv1)
    SCAT(kv2, w42, xv2)
    SCAT(kv3, w43, xv3)
    #undef SCAT
    __syncthreads();

    // fused epilogue: hyp[b][k][c0+cl] = (sum copies + ct)/(cnt+1)
    const int cl = tid & 3;
    #pragma unroll
    for (int it = 0; it < 4; ++it) {
        int k = (tid >> 2) + it * 64;
        float s = accs[0][cl][k] + accs[1][cl][k] + accs[2][cl][k] + accs[3][cl][k];
        float num = s + cents[((size_t)b * Cdim + c0 + cl) * Kdim + k];
        hyp[((size_t)(b * Kdim + k)) * Cdim + c0 + cl] = num / (float)(cnt[b * Kdim + k] + 1);
    }
}

extern "C" void kernel_launch(void* const* d_in, const int* in_sizes, int n_in,
                              void* d_out, int out_size, void* d_ws, size_t ws_size,
                              hipStream_t stream)
{
    const float* x     = (const float*)d_in[0];
    const float* cents = (const float*)d_in[1];
    const float* alpha = (const float*)d_in[2];
    const float* beta  = (const float*)d_in[3];

    float* hyp    = (float*)d_out;                                    // (B,K,C)
    float* simOut = (float*)d_out + (size_t)Bdim * Kdim * Cdim;       // (B,K,N)

    char* ws = (char*)d_ws;
    float* wArr  = (float*)(ws);                                 // 131072 B
    int*   kArr  = (int*)  (ws + 131072);                        // 131072 B
    int*   cnt   = (int*)  (ws + 262144);                        // 8192 B
    float* invc  = (float*)(ws + 270336);                        // 8192 B
    short* centH = (short*)(ws + 278528);                        // 3145728 B
    short* centM = (short*)(ws + 278528 + 3145728);              // 3145728 B
    short* centL = (short*)(ws + 278528 + 2 * 3145728);          // 3145728 B

    hipMemsetAsync(simOut, 0, (size_t)Bdim * Kdim * Ndim * sizeof(float), stream);

    prep_kernel<<<dim3(Bdim), dim3(256), 0, stream>>>(cents, invc, cnt);
    cvt_kernel<<<dim3(Bdim * 96), dim3(256), 0, stream>>>(cents, centH, centM, centL);
    sim_mfma_kernel<<<dim3(Bdim * (Ndim / NT)), dim3(256), 0, stream>>>(
        x, centH, centM, centL, alpha, beta, invc, simOut, wArr, kArr, cnt);
    agg_kernel<<<dim3(Bdim * (Cdim / CB2)), dim3(256), 0, stream>>>(
        x, cents, wArr, kArr, cnt, hyp);
}

// Round 11
// 272.342 us; speedup vs baseline: 1.0146x; 1.0146x over previous
//
#include <hip/hip_runtime.h>
#include <cmath>

#define Bdim 8
#define Cdim 768
#define Kdim 256
#define Ndim 4096
#define NT 64      // tokens per block in kernel 1
#define KC2 32     // C-chunk per MFMA stage (3-buffered)
#define NCH (Cdim / KC2)   // 24
#define CB2 4      // c-rows per block in kernel 2
#define NCOPY 4    // replicated LDS accumulators in kernel 2

typedef __bf16 bf16x8 __attribute__((ext_vector_type(8)));
typedef short  s16x8  __attribute__((ext_vector_type(8)));
typedef float  f32x4  __attribute__((ext_vector_type(4)));
union U8 { s16x8 s; bf16x8 b; };

// direct global->LDS DMA, 16B per lane, wave-uniform LDS base
typedef __attribute__((address_space(1))) const unsigned int g_u32;
typedef __attribute__((address_space(3))) unsigned int l_u32;
__device__ __forceinline__ void gload16(const void* g, void* l) {
    __builtin_amdgcn_global_load_lds((g_u32*)g, (l_u32*)l, 16, 0, 0);
}

// native LDS float atomic add (fire-and-forget ds_add_f32).
// hipcc's atomicAdd(float*) on LDS lowers to a CAS loop (~250 cyc/lane,
// latency-bound); ds_add_f32 is single-issue, no return, lgkmcnt-tracked.
// CAUTION: the compiler does NOT track this asm's lgkmcnt — caller must
// issue an explicit "s_waitcnt lgkmcnt(0)" before any barrier/read.
__device__ __forceinline__ void lds_fadd(float* p, float v) {
    auto lp = (__attribute__((address_space(3))) float*)p;
    asm volatile("ds_add_f32 %0, %1"
                 :: "v"((unsigned)(unsigned long long)lp), "v"(v) : "memory");
}

// three-level bf16 split, RNE at each level; v = h + m + l + eps, |eps| <= 2^-27 |v|
__device__ __forceinline__ void split3(float v, short& h, short& m, short& l) {
    unsigned u = __float_as_uint(v);
    unsigned th = u + 0x7FFFu + ((u >> 16) & 1u);
    h = (short)(th >> 16);
    float r1 = v - __uint_as_float(th & 0xFFFF0000u);      // exact
    unsigned u1 = __float_as_uint(r1);
    unsigned tm = u1 + 0x7FFFu + ((u1 >> 16) & 1u);
    m = (short)(tm >> 16);
    float r2 = r1 - __uint_as_float(tm & 0xFFFF0000u);     // exact
    unsigned u2 = __float_as_uint(r2);
    unsigned tl = u2 + 0x7FFFu + ((u2 >> 16) & 1u);
    l = (short)(tl >> 16);
}

// Prep: per batch b — centroid inverse norms (fp32, exact) + zero cnt.
__global__ __launch_bounds__(256) void prep_kernel(
    const float* __restrict__ cents, float* __restrict__ invc, int* __restrict__ cnt)
{
    __shared__ float red[4][Kdim];
    const int tid = threadIdx.x;
    const int b = blockIdx.x;
    const float* cb = cents + (size_t)b * Cdim * Kdim;
    const int q = tid & 63, g = tid >> 6;
    float4 ss = make_float4(0.f, 0.f, 0.f, 0.f);
    for (int r = g; r < Cdim; r += 4) {
        float4 v = *(const float4*)(cb + (size_t)r * Kdim + q * 4);
        ss.x = fmaf(v.x, v.x, ss.x); ss.y = fmaf(v.y, v.y, ss.y);
        ss.z = fmaf(v.z, v.z, ss.z); ss.w = fmaf(v.w, v.w, ss.w);
    }
    *(float4*)&red[g][q * 4] = ss;
    __syncthreads();
    float s = red[0][tid] + red[1][tid] + red[2][tid] + red[3][tid];
    invc[b * Kdim + tid] = 1.f / fmaxf(sqrtf(s), 1e-12f);
    cnt[b * Kdim + tid] = 0;
}

// Cvt: centroids -> split-3 bf16 planes in MFMA-fragment layout
// plane[(b*96 + c/8)*256 + k][8]: 8 consecutive c per 16B record.
__global__ __launch_bounds__(256) void cvt_kernel(
    const float* __restrict__ cents, short* __restrict__ centH,
    short* __restrict__ centM, short* __restrict__ centL)
{
    const int k = threadIdx.x;
    const int bc = blockIdx.x;                    // b*96 + c8
    const float* src = cents + ((size_t)(bc / 96) * Cdim + (size_t)(bc % 96) * 8) * Kdim + k;
    s16x8 H, M, L;
    #pragma unroll
    for (int e = 0; e < 8; ++e) {
        short h, m, l;
        split3(src[(size_t)e * Kdim], h, m, l);   // coalesced across lanes (k)
        H[e] = h; M[e] = m; L[e] = l;
    }
    ((s16x8*)centH)[(size_t)bc * 256 + k] = H;    // 16B coalesced stores
    ((s16x8*)centM)[(size_t)bc * 256 + k] = M;
    ((s16x8*)centL)[(size_t)bc * 256 + k] = L;
}

// Kernel 1: per (b, n-tile of 64): cos via split-3 bf16 MFMA, 6 passes
// (hh, hm, mh, hl, lh, mm) into ONE accumulator (noise ~1.5e-8 cos, safe).
// __launch_bounds__(256,2): 2 waves/SIMD is the grid cap anyway; this frees
// the full ~256-VGPR budget so acc + 24 fragments stay live (no remat).
__global__ __launch_bounds__(256, 2) void sim_mfma_kernel(
    const float* __restrict__ x,        // (B,C,N) fp32
    const short* __restrict__ centH,
    const short* __restrict__ centM,
    const short* __restrict__ centL,
    const float* __restrict__ alpha_p,
    const float* __restrict__ beta_p,
    const float* __restrict__ invc,     // (B,K) fp32
    float* __restrict__ simOut,         // (B,K,N), pre-zeroed
    float* __restrict__ wArr,
    int*   __restrict__ kArr,
    int*   __restrict__ cnt)
{
    __shared__ __align__(16) float sxf[3][KC2][NT];  // 24 KB fp32 x chunks
    __shared__ float invcS[Kdim];
    __shared__ float px[4][NT];
    __shared__ float invxS[NT];
    __shared__ float bwv[4][NT];
    __shared__ int   bwk[4][NT];

    const int tid  = threadIdx.x;
    const int lane = tid & 63;
    const int w    = tid >> 6;          // wave id: k-range [w*64, w*64+64)
    const int q    = lane >> 4;         // 0..3
    const int c15  = lane & 15;
    const int b    = blockIdx.x >> 6;
    const int n0   = (blockIdx.x & 63) * NT;
    const float* xb = x + (size_t)b * Cdim * Ndim;

    invcS[tid] = invc[b * Kdim + tid];
    const float alpha = alpha_p[0];
    const float beta  = beta_p[0];

    f32x4 acc[4][4];
    #pragma unroll
    for (int i = 0; i < 4; ++i)
        #pragma unroll
        for (int j = 0; j < 4; ++j) acc[i][j] = (f32x4){0.f, 0.f, 0.f, 0.f};

    float xn2p = 0.f;

    // exactly 2 DMA (vmcnt) ops per wave per STAGE
    #define STAGE(t_) do {                                                    \
        const int bf_ = (t_) % 3; const int c0_ = (t_) * KC2;                 \
        _Pragma("unroll")                                                     \
        for (int i_ = 0; i_ < 2; ++i_)                                        \
            gload16(xb + (size_t)(c0_ + w * 8 + i_ * 4 + q) * Ndim            \
                       + n0 + c15 * 4,                                        \
                    &sxf[bf_][w * 8 + i_ * 4][0]);                            \
    } while (0)

    STAGE(0);
    STAGE(1);

    const s16x8* cHb = (const s16x8*)centH + ((size_t)b * 96) * 256;
    const s16x8* cMb = (const s16x8*)centM + ((size_t)b * 96) * 256;
    const s16x8* cLb = (const s16x8*)centL + ((size_t)b * 96) * 256;

    for (int t = 0; t < NCH; ++t) {
        // retire everything except STAGE(t+1)'s 2 newest; chunk t ready
        asm volatile("s_waitcnt vmcnt(2)" ::: "memory");
        __builtin_amdgcn_s_barrier();
        __builtin_amdgcn_sched_barrier(0);

        const int cur = t % 3;

        // A fragments (12 16B loads, L2/L3-resident planes), before next STAGE
        U8 aH[4], aM[4], aL[4];
        {
            const size_t rowb = ((size_t)(t * 4 + q)) * 256 + w * 64 + c15;
            #pragma unroll
            for (int kf = 0; kf < 4; ++kf) {
                aH[kf].s = cHb[rowb + kf * 16];
                aM[kf].s = cMb[rowb + kf * 16];
                aL[kf].s = cLb[rowb + kf * 16];
            }
        }
        if (t + 2 < NCH) STAGE(t + 2);

        // x-norm partials (rows w*8..w*8+7, col = lane)
        #pragma unroll
        for (int r = 0; r < 8; ++r) {
            float v = sxf[cur][w * 8 + r][lane];
            xn2p = fmaf(v, v, xn2p);
        }

        // B fragments: split fp32 tile -> h/m/l bf16 in-register
        U8 bH[4], bM[4], bL[4];
        #pragma unroll
        for (int nf = 0; nf < 4; ++nf) {
            #pragma unroll
            for (int e = 0; e < 8; ++e) {
                short h, m, l;
                split3(sxf[cur][q * 8 + e][nf * 16 + c15], h, m, l);
                bH[nf].s[e] = h; bM[nf].s[e] = m; bL[nf].s[e] = l;
            }
        }

        // 6 passes x 16 fragment-MFMAs, pass-major, single accumulator
        #pragma unroll
        for (int kf = 0; kf < 4; ++kf)
            #pragma unroll
            for (int nf = 0; nf < 4; ++nf)
                acc[kf][nf] = __builtin_amdgcn_mfma_f32_16x16x32_bf16(
                    aH[kf].b, bH[nf].b, acc[kf][nf], 0, 0, 0);
        #pragma unroll
        for (int kf = 0; kf < 4; ++kf)
            #pragma unroll
            for (int nf = 0; nf < 4; ++nf)
                acc[kf][nf] = __builtin_amdgcn_mfma_f32_16x16x32_bf16(
                    aH[kf].b, bM[nf].b, acc[kf][nf], 0, 0, 0);
        #pragma unroll
        for (int kf = 0; kf < 4; ++kf)
            #pragma unroll
            for (int nf = 0; nf < 4; ++nf)
                acc[kf][nf] = __builtin_amdgcn_mfma_f32_16x16x32_bf16(
                    aM[kf].b, bH[nf].b, acc[kf][nf], 0, 0, 0);
        #pragma unroll
        for (int kf = 0; kf < 4; ++kf)
            #pragma unroll
            for (int nf = 0; nf < 4; ++nf)
                acc[kf][nf] = __builtin_amdgcn_mfma_f32_16x16x32_bf16(
                    aH[kf].b, bL[nf].b, acc[kf][nf], 0, 0, 0);
        #pragma unroll
        for (int kf = 0; kf < 4; ++kf)
            #pragma unroll
            for (int nf = 0; nf < 4; ++nf)
                acc[kf][nf] = __builtin_amdgcn_mfma_f32_16x16x32_bf16(
                    aL[kf].b, bH[nf].b, acc[kf][nf], 0, 0, 0);
        #pragma unroll
        for (int kf = 0; kf < 4; ++kf)
            #pragma unroll
            for (int nf = 0; nf < 4; ++nf)
                acc[kf][nf] = __builtin_amdgcn_mfma_f32_16x16x32_bf16(
                    aM[kf].b, bM[nf].b, acc[kf][nf], 0, 0, 0);
    }
    #undef STAGE

    __syncthreads();
    px[w][lane] = xn2p;
    __syncthreads();
    if (tid < NT) {
        float s = px[0][tid] + px[1][tid] + px[2][tid] + px[3][tid];
        invxS[tid] = 1.f / fmaxf(sqrtf(s), 1e-12f);
    }
    __syncthreads();

    // epilogue: cos -> sigmoid -> argmax (first-win = min-k on ties)
    // D layout: row(k_local) = q*4 + reg, col(n) = c15
    #pragma unroll
    for (int nf = 0; nf < 4; ++nf) {
        const float ivx = invxS[nf * 16 + c15];
        float best = -1.f; int bk = 0;
        #pragma unroll
        for (int kf = 0; kf < 4; ++kf) {
            float4 ic = *(const float4*)&invcS[w * 64 + kf * 16 + q * 4];
            #pragma unroll
            for (int r = 0; r < 4; ++r) {
                float cosv = acc[kf][nf][r] * ((const float*)&ic)[r] * ivx;
                float s = 1.f / (1.f + expf(-(beta + alpha * cosv)));
                int k = w * 64 + kf * 16 + q * 4 + r;
                if (s > best) { best = s; bk = k; }   // ascending k scan
            }
        }
        // reduce across q-groups (lanes l, l^16, l^32, l^48 share n)
        #pragma unroll
        for (int off = 16; off < 64; off <<= 1) {
            float ov = __shfl_xor(best, off);
            int   ok = __shfl_xor(bk, off);
            if (ov > best || (ov == best && ok < bk)) { best = ov; bk = ok; }
        }
        if (q == 0) { bwv[w][nf * 16 + c15] = best; bwk[w][nf * 16 + c15] = bk; }
    }
    __syncthreads();
    if (tid < NT) {
        float best = -1.f; int bk = 0;
        #pragma unroll
        for (int g = 0; g < 4; ++g) {    // ascending waves = ascending k
            float v = bwv[g][tid];
            if (v > best) { best = v; bk = bwk[g][tid]; }
        }
        int gn = b * Ndim + n0 + tid;
        wArr[gn] = best;
        kArr[gn] = bk;
        simOut[((size_t)(b * Kdim + bk)) * Ndim + n0 + tid] = best;
        atomicAdd(&cnt[b * Kdim + bk], 1);
    }
}

// Kernel 2: per (b, 4 c-rows): stream all N tokens; 4-way replicated LDS
// accumulators; native ds_add_f32 scatter + EXPLICIT lgkmcnt drain before
// the barrier (compiler can't see the asm's DS ops). Fused epilogue.
__global__ __launch_bounds__(256, 4) void agg_kernel(
    const float* __restrict__ x, const float* __restrict__ cents,
    const float* __restrict__ wArr, const int* __restrict__ kArr,
    const int* __restrict__ cnt, float* __restrict__ hyp)
{
    __shared__ float accs[NCOPY][CB2][Kdim + 1];
    const int tid = threadIdx.x;
    const int b  = blockIdx.x / (Cdim / CB2);
    const int c0 = (blockIdx.x % (Cdim / CB2)) * CB2;
    const int cp = tid & 3;
    const float* xb = x + ((size_t)b * Cdim + c0) * Ndim;

    for (int i = tid; i < NCOPY * CB2 * (Kdim + 1); i += 256) ((float*)accs)[i] = 0.f;
    __syncthreads();

    #pragma unroll
    for (int i = 0; i < 4; ++i) {
        int n = (tid + i * 256) * 4;
        int4   kv = *(const int4*)&kArr[b * Ndim + n];
        float4 w4 = *(const float4*)&wArr[b * Ndim + n];
        float4 xv[CB2];
        #pragma unroll
        for (int r = 0; r < CB2; ++r)
            xv[r] = *(const float4*)&xb[(size_t)r * Ndim + n];
        #pragma unroll
        for (int r = 0; r < CB2; ++r) {
            lds_fadd(&accs[cp][r][kv.x], w4.x * xv[r].x);
            lds_fadd(&accs[cp][r][kv.y], w4.y * xv[r].y);
            lds_fadd(&accs[cp][r][kv.z], w4.z * xv[r].z);
            lds_fadd(&accs[cp][r][kv.w], w4.w * xv[r].w);
        }
    }
    // the compiler doesn't track the asm ds_add_f32s -> drain them OURSELVES
    // before the barrier, else waves cross with adds still in flight (r10 bug)
    asm volatile("s_waitcnt lgkmcnt(0)" ::: "memory");
    __builtin_amdgcn_sched_barrier(0);
    __syncthreads();

    // fused epilogue: hyp[b][k][c0+cl] = (sum copies + ct)/(cnt+1)
    const int cl = tid & 3;
    #pragma unroll
    for (int it = 0; it < 4; ++it) {
        int k = (tid >> 2) + it * 64;
        float s = accs[0][cl][k] + accs[1][cl][k] + accs[2][cl][k] + accs[3][cl][k];
        float num = s + cents[((size_t)b * Cdim + c0 + cl) * Kdim + k];
        hyp[((size_t)(b * Kdim + k)) * Cdim + c0 + cl] = num / (float)(cnt[b * Kdim + k] + 1);
    }
}

extern "C" void kernel_launch(void* const* d_in, const int* in_sizes, int n_in,
                              void* d_out, int out_size, void* d_ws, size_t ws_size,
                              hipStream_t stream)
{
    const float* x     = (const float*)d_in[0];
    const float* cents = (const float*)d_in[1];
    const float* alpha = (const float*)d_in[2];
    const float* beta  = (const float*)d_in[3];

    float* hyp    = (float*)d_out;                                    // (B,K,C)
    float* simOut = (float*)d_out + (size_t)Bdim * Kdim * Cdim;       // (B,K,N)

    char* ws = (char*)d_ws;
    float* wArr  = (float*)(ws);                                 // 131072 B
    int*   kArr  = (int*)  (ws + 131072);                        // 131072 B
    int*   cnt   = (int*)  (ws + 262144);                        // 8192 B
    float* invc  = (float*)(ws + 270336);                        // 8192 B
    short* centH = (short*)(ws + 278528);                        // 3145728 B
    short* centM = (short*)(ws + 278528 + 3145728);              // 3145728 B
    short* centL = (short*)(ws + 278528 + 2 * 3145728);          // 3145728 B

    hipMemsetAsync(simOut, 0, (size_t)Bdim * Kdim * Ndim * sizeof(float), stream);

    prep_kernel<<<dim3(Bdim), dim3(256), 0, stream>>>(cents, invc, cnt);
    cvt_kernel<<<dim3(Bdim * 96), dim3(256), 0, stream>>>(cents, centH, centM, centL);
    sim_mfma_kernel<<<dim3(Bdim * (Ndim / NT)), dim3(256), 0, stream>>>(
        x, centH, centM, centL, alpha, beta, invc, simOut, wArr, kArr, cnt);
    agg_kernel<<<dim3(Bdim * (Cdim / CB2)), dim3(256), 0, stream>>>(
        x, cents, wArr, kArr, cnt, hyp);
}